// Round 6
// baseline (1067.389 us; speedup 1.0000x reference)
//
#include <hip/hip_runtime.h>
#include <hip/hip_fp16.h>

#define N_NODES 100000
#define N_EDGES 1250000
#define F 64
#define NB 1563                 // buckets of 64 nodes: 1562*64 + 32
#define TP2 65                  // LDS accumulator pitch (bank-conflict-free)
#define EPB 4096                // edges per partition/hist block
#define NPARTB ((N_EDGES + EPB - 1) / EPB)  // 306

// ---------------- K0: x -> fp16 (halves gather bytes in agg) ----------------
__global__ __launch_bounds__(256) void xconv_kernel(const float4* __restrict__ x4,
                                                    __half* __restrict__ xh) {
    int gid = blockIdx.x * 256 + threadIdx.x;
    if (gid < N_NODES * F / 4) {
        float4 v = x4[gid];
        __half2 h01 = __floats2half2_rn(v.x, v.y);
        __half2 h23 = __floats2half2_rn(v.z, v.w);
        int2 pk;
        pk.x = *(const int*)&h01;
        pk.y = *(const int*)&h23;
        ((int2*)xh)[gid] = pk;
    }
}

// ---------------- K1: bucket histogram (LDS-staged; hist pre-zeroed) --------
__global__ __launch_bounds__(256) void bhist_kernel(const int* __restrict__ ei,
                                                    int* __restrict__ hist) {
    __shared__ int lh[NB];
    int t = threadIdx.x;
    for (int b = t; b < NB; b += 256) lh[b] = 0;
    __syncthreads();
    int e0 = blockIdx.x * EPB;
    #pragma unroll
    for (int j = 0; j < EPB / 256; ++j) {
        int e = e0 + j * 256 + t;
        if (e < N_EDGES) atomicAdd(&lh[ei[N_EDGES + e] >> 6], 1);
    }
    __syncthreads();
    for (int b = t; b < NB; b += 256) {
        int c = lh[b];
        if (c) atomicAdd(&hist[b], c);
    }
}

// ---------------- K2: exclusive scan of 1563 bucket counts ------------------
#define SCHUNK 7  // 256*7 = 1792 >= NB
__global__ __launch_bounds__(256) void bscan_kernel(const int* __restrict__ hist,
                                                    int* __restrict__ gbase,
                                                    int* __restrict__ gcursor) {
    __shared__ int wsum[4];
    int t = threadIdx.x, lane = t & 63, wave = t >> 6;
    int v[SCHUNK]; int s = 0;
    #pragma unroll
    for (int j = 0; j < SCHUNK; ++j) {
        int b = t * SCHUNK + j;
        v[j] = (b < NB) ? hist[b] : 0;
        s += v[j];
    }
    int xs = s;
    for (int d = 1; d < 64; d <<= 1) { int y = __shfl_up(xs, d); if (lane >= d) xs += y; }
    if (lane == 63) wsum[wave] = xs;
    __syncthreads();
    int pre = xs - s;
    for (int w = 0; w < wave; ++w) pre += wsum[w];
    #pragma unroll
    for (int j = 0; j < SCHUNK; ++j) {
        int b = t * SCHUNK + j;
        if (b < NB) { gbase[b] = pre; gcursor[b] = pre; pre += v[j]; }
    }
    if (t == 255) gbase[NB] = pre;  // == N_EDGES
}

// ---------------- K3: bucket partition, all scattered writes in LDS ---------
// 512 thr x 8 edges. Local counting-sort into LDS staging; per-bucket global
// run reservation (1 atomic per nonempty (block,bucket)); coalesced writeout.
#define PEPT (EPB / 512)  // 8
__global__ __launch_bounds__(512) void part_kernel(const int* __restrict__ ei,
                                                   const float* __restrict__ ew,
                                                   int* __restrict__ gcursor,
                                                   int2* __restrict__ pay) {
    __shared__ int   cnt[NB];      // counts -> exclusive scan -> cursor
    __shared__ int   gdelta[NB];   // global run start - local run start
    __shared__ int2  stage[EPB];
    __shared__ short stageB[EPB];
    __shared__ int   wsum[8];
    int t = threadIdx.x, lane = t & 63, wave = t >> 6;

    for (int b = t; b < NB; b += 512) cnt[b] = 0;
    __syncthreads();

    int e0 = blockIdx.x * EPB;
    int m = min(EPB, N_EDGES - e0);
    int myr[PEPT];
    #pragma unroll
    for (int j = 0; j < PEPT; ++j) {
        int e = e0 + j * 512 + t;
        myr[j] = (e < N_EDGES) ? ei[N_EDGES + e] : -1;
        if (myr[j] >= 0) atomicAdd(&cnt[myr[j] >> 6], 1);
    }
    __syncthreads();

    // reservation (reads cnt) + per-thread chunk copy for the local scan
    for (int b = t; b < NB; b += 512) {
        int c = cnt[b];
        gdelta[b] = c ? atomicAdd(&gcursor[b], c) : 0;  // global run start
    }
    int v[4]; int s = 0;  // 512*4 = 2048 >= NB
    #pragma unroll
    for (int j = 0; j < 4; ++j) {
        int b = t * 4 + j;
        v[j] = (b < NB) ? cnt[b] : 0;
        s += v[j];
    }
    __syncthreads();

    int xs = s;
    for (int d = 1; d < 64; d <<= 1) { int y = __shfl_up(xs, d); if (lane >= d) xs += y; }
    if (lane == 63) wsum[wave] = xs;
    __syncthreads();
    int pre = xs - s;
    for (int w = 0; w < wave; ++w) pre += wsum[w];
    #pragma unroll
    for (int j = 0; j < 4; ++j) {
        int b = t * 4 + j;
        if (b < NB) { cnt[b] = pre; pre += v[j]; }   // cnt := local exclusive scan
    }
    __syncthreads();
    for (int b = t; b < NB; b += 512) gdelta[b] -= cnt[b];  // global = gdelta[b] + slot
    __syncthreads();

    // local scatter into LDS staging (cnt doubles as local cursor)
    #pragma unroll
    for (int j = 0; j < PEPT; ++j) {
        int e = e0 + j * 512 + t;
        if (e < N_EDGES) {
            int r = myr[j];
            int b = r >> 6;
            int slot = atomicAdd(&cnt[b], 1);
            __half2 h = __floats2half2_rn(ew[e], ew[N_EDGES + e]);
            int2 p;
            p.x = ei[e] | ((r & 63) << 20);  // src (20b) | local node (6b)
            p.y = *(const int*)&h;
            stage[slot] = p;
            stageB[slot] = (short)b;
        }
    }
    __syncthreads();

    // coalesced writeout: slot s of bucket b -> pay[gdelta[b] + s]
    for (int s2 = t; s2 < m; s2 += 512) {
        int b = stageB[s2];
        pay[gdelta[b] + s2] = stage[s2];
    }
}

// ---------------- K4: fused bucket aggregation (LDS f32 atomics) + GEMM -----
// Block = 1 bucket (64 nodes). Edge loop: wave-strided, 2-stage pipelined;
// accumulate via ds_add_f32 into [64][65] tiles (banks (rl+lane)%32: 2-way,
// free). Then 64x64x64 GEMM x 2 dirs from LDS, W/bias broadcast from L1.
template<bool HALFX>
__global__ __launch_bounds__(512, 4) void agg_gemm_kernel(
    const float* __restrict__ x, const __half* __restrict__ xh,
    const int* __restrict__ gbase, const int2* __restrict__ pay,
    const float* __restrict__ Wsrc, const float* __restrict__ Wdst,
    const float* __restrict__ bsrc, const float* __restrict__ bdst,
    float* __restrict__ outA, float* __restrict__ outB)
{
    __shared__ float accA[64 * TP2];
    __shared__ float accB[64 * TP2];
    int t = threadIdx.x, lane = t & 63, w = t >> 6;
    for (int i = t; i < 64 * TP2; i += 512) { accA[i] = 0.f; accB[i] = 0.f; }
    int bkt = blockIdx.x;
    int beg = gbase[bkt], end = gbase[bkt + 1];
    __syncthreads();

#define XLOAD(p) (HALFX ? __half2float(xh[(size_t)((p).x & 0xFFFFF) * F + lane]) \
                        : x[(size_t)((p).x & 0xFFFFF) * F + lane])

    int i = beg + w;
    int i2 = i + 8;
    int2 pc = {0, 0}, pn = {0, 0};
    float vc = 0.f;
    if (i < end) pc = pay[i];
    if (i2 < end) pn = pay[i2];
    if (i < end) vc = XLOAD(pc);
    while (i < end) {
        int i3 = i2 + 8;
        int2 pnn = {0, 0};
        float vn = 0.f;
        if (i3 < end) pnn = pay[i3];
        if (i2 < end) vn = XLOAD(pn);
        float2 wf = __half22float2(*(const __half2*)&pc.y);
        int rl = (pc.x >> 20) & 63;
        atomicAdd(&accA[rl * TP2 + lane], vc * wf.x);
        atomicAdd(&accB[rl * TP2 + lane], vc * wf.y);
        pc = pn; vc = vn; pn = pnn;
        i = i2; i2 = i3;
    }
#undef XLOAD
    __syncthreads();

    // GEMM: 512 threads = 2 dirs x (16 j-groups x 16 n-groups); 4n x 4j each.
    int dir = t >> 8;
    int q = t & 255;
    int j4 = (q & 15) * 4;
    int n4 = (q >> 4) * 4;
    const float* W    = dir ? Wdst : Wsrc;
    const float* bias = dir ? bdst : bsrc;
    const float* tile = dir ? accB : accA;
    float* out        = dir ? outB : outA;

    float4 bj = *(const float4*)&bias[j4];
    float4 a0 = bj, a1 = bj, a2 = bj, a3 = bj;
    #pragma unroll 8
    for (int k = 0; k < F; ++k) {
        float4 wv = *(const float4*)&W[k * F + j4];
        float v0 = tile[(n4 + 0) * TP2 + k];
        float v1 = tile[(n4 + 1) * TP2 + k];
        float v2 = tile[(n4 + 2) * TP2 + k];
        float v3 = tile[(n4 + 3) * TP2 + k];
        a0.x += v0 * wv.x; a0.y += v0 * wv.y; a0.z += v0 * wv.z; a0.w += v0 * wv.w;
        a1.x += v1 * wv.x; a1.y += v1 * wv.y; a1.z += v1 * wv.z; a1.w += v1 * wv.w;
        a2.x += v2 * wv.x; a2.y += v2 * wv.y; a2.z += v2 * wv.z; a2.w += v2 * wv.w;
        a3.x += v3 * wv.x; a3.y += v3 * wv.y; a3.z += v3 * wv.z; a3.w += v3 * wv.w;
    }
    float4 as[4] = {a0, a1, a2, a3};
    int nb = bkt * 64 + n4;
    #pragma unroll
    for (int ii = 0; ii < 4; ++ii) {
        int n = nb + ii;
        if (n < N_NODES) *(float4*)&out[(size_t)n * F + j4] = as[ii];
    }
}

// ---------------- fallback path (atomic) ----------------

__global__ __launch_bounds__(256) void scatter_fallback(const float4* __restrict__ x4,
                                                        const int* __restrict__ ei,
                                                        const float* __restrict__ ew,
                                                        float* __restrict__ aggA,
                                                        float* __restrict__ aggB) {
    int t = blockIdx.x * blockDim.x + threadIdx.x;
    int e = t >> 4;
    int lane16 = t & 15;
    if (e >= N_EDGES) return;
    int src = ei[e], dst = ei[N_EDGES + e];
    float w0 = ew[e], w1 = ew[N_EDGES + e];
    float4 v = x4[(size_t)src * 16 + lane16];
    int base = dst * F + lane16 * 4;
    atomicAdd(&aggA[base + 0], v.x * w0); atomicAdd(&aggA[base + 1], v.y * w0);
    atomicAdd(&aggA[base + 2], v.z * w0); atomicAdd(&aggA[base + 3], v.w * w0);
    atomicAdd(&aggB[base + 0], v.x * w1); atomicAdd(&aggB[base + 1], v.y * w1);
    atomicAdd(&aggB[base + 2], v.z * w1); atomicAdd(&aggB[base + 3], v.w * w1);
}

__global__ __launch_bounds__(256) void matmul_fallback(float* __restrict__ outA, float* __restrict__ outB,
                                                       const float* __restrict__ Wsrc, const float* __restrict__ Wdst,
                                                       const float* __restrict__ bsrc, const float* __restrict__ bdst) {
    __shared__ float lWs[F * F];
    __shared__ float lWd[F * F];
    for (int i = threadIdx.x; i < F * F / 4; i += blockDim.x) {
        ((float4*)lWs)[i] = ((const float4*)Wsrc)[i];
        ((float4*)lWd)[i] = ((const float4*)Wdst)[i];
    }
    __syncthreads();
    int wave = (blockIdx.x * blockDim.x + threadIdx.x) >> 6;
    int lane = threadIdx.x & 63;
    if (wave >= N_NODES) return;
    size_t rowbase = (size_t)wave * F;
    float a0 = outA[rowbase + lane], a1 = outB[rowbase + lane];
    float acc0 = bsrc[lane], acc1 = bdst[lane];
    #pragma unroll
    for (int k = 0; k < F; ++k) {
        acc0 += __shfl(a0, k) * lWs[k * F + lane];
        acc1 += __shfl(a1, k) * lWd[k * F + lane];
    }
    outA[rowbase + lane] = acc0;
    outB[rowbase + lane] = acc1;
}

// ---------------- launch ----------------

template<bool HALFX>
static void run_path(const float* x, const int* ei, const float* ew,
                     const float* Wsrc, const float* Wdst,
                     const float* bsrc, const float* bdst,
                     float* outA, float* outB, char* ws, hipStream_t stream) {
    // ws layout (128-aligned)
    int*  hist    = (int*)(ws + 0);          // NB*4 -> 6400
    int*  gbase   = (int*)(ws + 6400);       // (NB+1)*4 -> 6400
    int*  gcursor = (int*)(ws + 12800);      // NB*4 -> 6400
    int2* pay     = (int2*)(ws + 19200);     // E*8 = 10,000,000
    __half* xh    = (__half*)(ws + 10019200);// N*F*2 (T1 only)

    hipMemsetAsync(hist, 0, 6400, stream);
    if (HALFX) xconv_kernel<<<(N_NODES * F / 4 + 255) / 256, 256, 0, stream>>>((const float4*)x, xh);
    bhist_kernel<<<NPARTB, 256, 0, stream>>>(ei, hist);
    bscan_kernel<<<1, 256, 0, stream>>>(hist, gbase, gcursor);
    part_kernel<<<NPARTB, 512, 0, stream>>>(ei, ew, gcursor, pay);
    agg_gemm_kernel<HALFX><<<NB, 512, 0, stream>>>(
        x, xh, gbase, pay, Wsrc, Wdst, bsrc, bdst, outA, outB);
}

extern "C" void kernel_launch(void* const* d_in, const int* in_sizes, int n_in,
                              void* d_out, int out_size, void* d_ws, size_t ws_size,
                              hipStream_t stream) {
    const float* x    = (const float*)d_in[0];
    const int*   ei   = (const int*)d_in[1];
    const float* ew   = (const float*)d_in[2];
    const float* Wsrc = (const float*)d_in[3];
    const float* Wdst = (const float*)d_in[4];
    const float* bsrc = (const float*)d_in[5];
    const float* bdst = (const float*)d_in[6];

    float* outA = (float*)d_out;
    float* outB = (float*)d_out + (size_t)N_NODES * F;

    const size_t REQ_T1 = 22819200;  // with fp16 x copy
    const size_t REQ_T2 = 10019200;  // without

    if (ws_size >= REQ_T1) {
        run_path<true>(x, ei, ew, Wsrc, Wdst, bsrc, bdst, outA, outB, (char*)d_ws, stream);
    } else if (ws_size >= REQ_T2) {
        run_path<false>(x, ei, ew, Wsrc, Wdst, bsrc, bdst, outA, outB, (char*)d_ws, stream);
    } else {
        hipMemsetAsync(d_out, 0, (size_t)out_size * sizeof(float), stream);
        int blocks_scatter = (N_EDGES * 16 + 255) / 256;
        scatter_fallback<<<blocks_scatter, 256, 0, stream>>>((const float4*)x, ei, ew, outA, outB);
        int blocks_mm = (N_NODES * 64 + 255) / 256;
        matmul_fallback<<<blocks_mm, 256, 0, stream>>>(outA, outB, Wsrc, Wdst, bsrc, bdst);
    }
}